// Round 1
// baseline (71.798 us; speedup 1.0000x reference)
//
#include <hip/hip_runtime.h>

// BatchedLUTNodes: out[b,n] = multilinear interpolation of tables[n, 0..63]
// at coordinates x[b,n,0..5] (clipped to [0,1]).
//
// BATCH=128, NUM_NODES=8192, N_INPUTS=6, N_ENTRIES=64.
//
// Algorithm: 6 levels of pairwise lerp over the 64-entry table (63 FMAs per
// output) -- algebraically identical to the reference's weight-product + dot.
//
// Tiling: block = 256 threads handles 64 nodes x 32 batches.
//   - table tile (64x64 f32 = 16 KB) staged in LDS, rows padded to 65 floats
//     (bank = (row + col) % 32 -> 2 lanes/bank on row reads = conflict-free).
//   - each thread owns one node, keeps its 64-entry table in registers,
//     loops over 8 batches -> LDS reads amortized to 8 per output.

#define THREADS 256
#define NPB 64   // nodes per block
#define BPB 32   // batches per block
#define PAD 65   // padded LDS row length

__global__ __launch_bounds__(THREADS)
void lut_fold_kernel(const float* __restrict__ x,
                     const float* __restrict__ tables,
                     float* __restrict__ out) {
    __shared__ float lt[NPB * PAD];

    const int tid       = threadIdx.x;
    const int node_tile = blockIdx.x & 127;   // NUM_NODES / NPB = 128 tiles
    const int bgroup    = blockIdx.x >> 7;    // 0..3 batch groups
    const int node0     = node_tile * NPB;
    const int b0        = bgroup * BPB;

    // ---- Stage 64x64 table tile into LDS (coalesced global reads) ----
    {
        const float* gt = tables + (long)node0 * 64;
        #pragma unroll
        for (int k = 0; k < (NPB * 64) / THREADS; ++k) {
            const int g = tid + THREADS * k;          // 0..4095
            lt[(g >> 6) * PAD + (g & 63)] = gt[g];    // 2 lanes/bank: free
        }
    }
    __syncthreads();

    const int n_local = tid & 63;   // node within tile
    const int bq      = tid >> 6;   // 0..3: batch sub-group
    const int n       = node0 + n_local;

    // ---- Pull this node's table into registers (reused across 8 batches) ----
    float t[64];
    #pragma unroll
    for (int e = 0; e < 64; ++e) t[e] = lt[n_local * PAD + e];

    // ---- 8 batches per thread ----
    for (int bl = 0; bl < BPB / 4; ++bl) {
        const int b = b0 + bq * (BPB / 4) + bl;

        // x[b][n][0..5]: lanes are consecutive n -> contiguous 24 B/lane.
        const float2* xp = (const float2*)(x + ((long)b * 8192 + n) * 6);
        const float2 p0 = xp[0];
        const float2 p1 = xp[1];
        const float2 p2 = xp[2];
        const float x0 = fminf(fmaxf(p0.x, 0.f), 1.f);
        const float x1 = fminf(fmaxf(p0.y, 0.f), 1.f);
        const float x2 = fminf(fmaxf(p1.x, 0.f), 1.f);
        const float x3 = fminf(fmaxf(p1.y, 0.f), 1.f);
        const float x4 = fminf(fmaxf(p2.x, 0.f), 1.f);
        const float x5 = fminf(fmaxf(p2.y, 0.f), 1.f);

        // ---- 6-level multilinear fold: lerp(lo, hi, xi) = fma(xi, hi-lo, lo)
        float a[32];
        #pragma unroll
        for (int j = 0; j < 32; ++j) a[j] = fmaf(x0, t[2*j+1] - t[2*j], t[2*j]);
        #pragma unroll
        for (int j = 0; j < 16; ++j) a[j] = fmaf(x1, a[2*j+1] - a[2*j], a[2*j]);
        #pragma unroll
        for (int j = 0; j < 8;  ++j) a[j] = fmaf(x2, a[2*j+1] - a[2*j], a[2*j]);
        #pragma unroll
        for (int j = 0; j < 4;  ++j) a[j] = fmaf(x3, a[2*j+1] - a[2*j], a[2*j]);
        #pragma unroll
        for (int j = 0; j < 2;  ++j) a[j] = fmaf(x4, a[2*j+1] - a[2*j], a[2*j]);
        const float r = fmaf(x5, a[1] - a[0], a[0]);

        out[(long)b * 8192 + n] = r;   // coalesced 4 B/lane
    }
}

extern "C" void kernel_launch(void* const* d_in, const int* in_sizes, int n_in,
                              void* d_out, int out_size, void* d_ws, size_t ws_size,
                              hipStream_t stream) {
    const float* x      = (const float*)d_in[0];   // 128*8192*6 f32
    const float* tables = (const float*)d_in[1];   // 8192*64 f32
    float* out          = (float*)d_out;           // 128*8192 f32

    dim3 grid(512);   // 128 node tiles x 4 batch groups
    dim3 block(THREADS);
    hipLaunchKernelGGL(lut_fold_kernel, grid, block, 0, stream, x, tables, out);
}

// Round 2
// 70.838 us; speedup vs baseline: 1.0136x; 1.0136x over previous
//
#include <hip/hip_runtime.h>

// BatchedLUTNodes: out[b,n] = 6-D multilinear interpolation of tables[n,0..63]
// at coords x[b,n,0..5] clipped to [0,1]. 63 lerps/output == reference's
// weight-product + dot (verified R1, absmax 3.9e-3 << 1.8e-2).
//
// R2 change vs R1: BPB 32->16, grid 512->1024 (4 blocks/CU, 16 waves/CU vs
// R1's 8 waves/CU) for memory-latency hiding; dwordx4 table staging; batch
// loop fully unrolled with x-loads hoisted ahead of the fold chains.
//
// LDS layout: rows padded to 65 floats. Register-fill loop (lane=row r,
// scans e): bank = (65r+e)%32 = (r+e)%32 -> exactly 2 lanes/bank = free
// (m136). Do NOT "improve" to b128: any stride-64/68 layout puts same-e
// lane reads on <=8 banks (8-way = 2.94x), measured worse than b32 x64.

#define THREADS 256
#define NPB 64   // nodes per block
#define BPB 16   // batches per block
#define PAD 65   // padded LDS row length (see bank note above)

__global__ __launch_bounds__(THREADS)
void lut_fold_kernel(const float* __restrict__ x,
                     const float* __restrict__ tables,
                     float* __restrict__ out) {
    __shared__ float lt[NPB * PAD];

    const int tid       = threadIdx.x;
    const int node_tile = blockIdx.x & 127;   // 128 node tiles
    const int bgroup    = blockIdx.x >> 7;    // 0..7 batch groups
    const int node0     = node_tile * NPB;
    const int b0        = bgroup * BPB;

    // ---- Stage 64x64 table tile into LDS: 4x global_load_dwordx4/thread ----
    {
        const float4* gt4 = (const float4*)(tables + (long)node0 * 64);
        #pragma unroll
        for (int k = 0; k < (NPB * 64) / (THREADS * 4); ++k) {
            const int g4 = tid + THREADS * k;        // float4 index 0..1023
            const float4 v = gt4[g4];                // coalesced 16 B/lane
            const int row = g4 >> 4;                 // 16 float4 per row
            const int col = (g4 & 15) * 4;
            float* d = &lt[row * PAD + col];
            d[0] = v.x; d[1] = v.y; d[2] = v.z; d[3] = v.w;
        }
    }
    __syncthreads();

    const int n_local = tid & 63;   // node within tile (== lane)
    const int bq      = tid >> 6;   // 0..3 batch sub-group
    const int n       = node0 + n_local;
    const int bbase   = b0 + bq * (BPB / 4);

    // ---- This node's table into registers (reused across 4 batches) ----
    float t[64];
    #pragma unroll
    for (int e = 0; e < 64; ++e) t[e] = lt[n_local * PAD + e];

    // ---- Hoist all x loads (12 float2, contiguous 24 B/lane) ----
    float2 p[4][3];
    #pragma unroll
    for (int bl = 0; bl < 4; ++bl) {
        const float2* xp = (const float2*)(x + ((long)(bbase + bl) * 8192 + n) * 6);
        p[bl][0] = xp[0];
        p[bl][1] = xp[1];
        p[bl][2] = xp[2];
    }

    // ---- 4 independent 6-level folds ----
    #pragma unroll
    for (int bl = 0; bl < 4; ++bl) {
        const float x0 = fminf(fmaxf(p[bl][0].x, 0.f), 1.f);
        const float x1 = fminf(fmaxf(p[bl][0].y, 0.f), 1.f);
        const float x2 = fminf(fmaxf(p[bl][1].x, 0.f), 1.f);
        const float x3 = fminf(fmaxf(p[bl][1].y, 0.f), 1.f);
        const float x4 = fminf(fmaxf(p[bl][2].x, 0.f), 1.f);
        const float x5 = fminf(fmaxf(p[bl][2].y, 0.f), 1.f);

        float a[32];
        #pragma unroll
        for (int j = 0; j < 32; ++j) a[j] = fmaf(x0, t[2*j+1] - t[2*j], t[2*j]);
        #pragma unroll
        for (int j = 0; j < 16; ++j) a[j] = fmaf(x1, a[2*j+1] - a[2*j], a[2*j]);
        #pragma unroll
        for (int j = 0; j < 8;  ++j) a[j] = fmaf(x2, a[2*j+1] - a[2*j], a[2*j]);
        #pragma unroll
        for (int j = 0; j < 4;  ++j) a[j] = fmaf(x3, a[2*j+1] - a[2*j], a[2*j]);
        #pragma unroll
        for (int j = 0; j < 2;  ++j) a[j] = fmaf(x4, a[2*j+1] - a[2*j], a[2*j]);
        const float r = fmaf(x5, a[1] - a[0], a[0]);

        out[(long)(bbase + bl) * 8192 + n] = r;   // coalesced
    }
}

extern "C" void kernel_launch(void* const* d_in, const int* in_sizes, int n_in,
                              void* d_out, int out_size, void* d_ws, size_t ws_size,
                              hipStream_t stream) {
    const float* x      = (const float*)d_in[0];   // 128*8192*6 f32
    const float* tables = (const float*)d_in[1];   // 8192*64 f32
    float* out          = (float*)d_out;           // 128*8192 f32

    dim3 grid(1024);  // 128 node tiles x 8 batch groups = 4 blocks/CU
    dim3 block(THREADS);
    hipLaunchKernelGGL(lut_fold_kernel, grid, block, 0, stream, x, tables, out);
}